// Round 1
// baseline (603.678 us; speedup 1.0000x reference)
//
#include <hip/hip_runtime.h>

#define LDS_AS __attribute__((address_space(3)))
#define GLB_AS __attribute__((address_space(1)))

typedef __attribute__((ext_vector_type(8))) short bf16x8;   // 8 bf16 = 4 VGPRs (A/B frag)
typedef __attribute__((ext_vector_type(4))) float f32x4;    // C/D frag

static constexpr int NH = 4;
static constexpr int T  = 2048;
static constexpr int N  = 8192;
static constexpr int D  = 256;

__device__ inline unsigned short f2bf(float f) {
    unsigned int u = __float_as_uint(f);
    u += 0x7FFFu + ((u >> 16) & 1u);   // round-to-nearest-even
    return (unsigned short)(u >> 16);
}

__device__ inline void gl2lds16(const void* g, void* l) {
    __builtin_amdgcn_global_load_lds((GLB_AS void*)g, (LDS_AS void*)l, 16, 0, 0);
}

// ---------------- RoPE + bf16 cast: QR[h][t][n] ----------------
__global__ void rope_kernel(const float* __restrict__ Q, unsigned short* __restrict__ QR) {
    int g = blockIdx.x * 256 + threadIdx.x;     // one thread = 4 consecutive elements
    int base = g << 2;
    int n = base & (N - 1);
    int t = (base >> 13) & (T - 1);
    const float4 q = *(const float4*)(Q + (size_t)base);
    float tf = (float)t;
    const float inv2pi = 0.15915494309189535f;
    float f0 = exp2f((float)n       * (-1.0f / 512.0f)) * inv2pi;
    float f1 = exp2f((float)(n + 2) * (-1.0f / 512.0f)) * inv2pi;
    float r0 = tf * f0; r0 -= floorf(r0);
    float r1 = tf * f1; r1 -= floorf(r1);
    float s0 = __builtin_amdgcn_sinf(r0), c0 = __builtin_amdgcn_cosf(r0);
    float s1 = __builtin_amdgcn_sinf(r1), c1 = __builtin_amdgcn_cosf(r1);
    ushort4 o;
    o.x = f2bf(q.x * c0 - q.y * s0);
    o.y = f2bf(q.y * c0 + q.x * s0);
    o.z = f2bf(q.z * c1 - q.w * s1);
    o.w = f2bf(q.w * c1 + q.z * s1);
    *(ushort4*)(QR + (size_t)base) = o;
}

// ---------------- V -> Vt bf16 transpose via LDS: Vt[d][t] = bf16(V[t][d]) ----------------
__global__ void vt_kernel(const float* __restrict__ V, unsigned short* __restrict__ Vt) {
    __shared__ unsigned short tile[64 * 65];
    int tb = blockIdx.x >> 2, db = blockIdx.x & 3;
    int t0 = tb * 64, d0 = db * 64;
    int tid = threadIdx.x;
    #pragma unroll
    for (int r = 0; r < 16; r++) {
        int idx = tid + r * 256;
        int tl = idx >> 6, dl = idx & 63;
        tile[tl * 65 + dl] = f2bf(V[(size_t)(t0 + tl) * D + d0 + dl]);
    }
    __syncthreads();
    #pragma unroll
    for (int r = 0; r < 16; r++) {
        int idx = tid + r * 256;
        int dl = idx >> 6, tl = idx & 63;
        Vt[(size_t)(d0 + dl) * T + t0 + tl] = tile[tl * 65 + dl];
    }
}

// ---------------- GEMM1 v3: 128(t) x 256(s) tile, LDS double-buffer, 1 barrier/iter ----
// 4 waves as 2x2; wave tile 64x128 (4 x 8 frags of 16x16). Tasks: bj*256 <= bi*128 region.
__global__ __launch_bounds__(256, 2) void gemm1_kernel(const unsigned short* __restrict__ QR,
                                                       unsigned short* __restrict__ S, int KS) {
    __shared__ __align__(16) unsigned short As[2][128 * 32];   // 8 KB each
    __shared__ __align__(16) unsigned short Bs[2][256 * 32];   // 16 KB each

    int bx = blockIdx.x;
    int per_h = 72 * KS;
    int h = bx / per_h;
    int rem = bx % per_h;
    int task = rem / KS;
    int ks = rem % KS;
    // decode (bi, bj): bj in [0, bi/2]; counts 1,1,2,2,...,8,8 sum=72
    int bi = 0, cum = 0;
    for (; bi < 16; bi++) { int nb = (bi >> 1) + 1; if (cum + nb > task) break; cum += nb; }
    int bj = task - cum;

    const unsigned short* A = QR + (size_t)h * T * N + (size_t)bi * 128 * N;
    const unsigned short* B = QR + (size_t)h * T * N + (size_t)bj * 256 * N;

    int KN = N / KS;
    int k_begin = ks * KN;
    int nit = KN / 32;

    int tid = threadIdx.x;
    int lane = tid & 63, wave = tid >> 6;
    int wm = wave >> 1, wn = wave & 1;
    int quad = lane >> 4, l16 = lane & 15;
    int srow = tid >> 2;
    int scol = (tid & 3) * 8;

    f32x4 acc[4][8];
    #pragma unroll
    for (int i = 0; i < 4; i++)
        #pragma unroll
        for (int j = 0; j < 8; j++)
            #pragma unroll
            for (int r = 0; r < 4; r++) acc[i][j][r] = 0.0f;

    // preloop stage into buffer 0
    {
        int k0 = k_begin;
        gl2lds16(A + (size_t)srow * N + k0 + scol,         &As[0][srow * 32 + scol]);
        gl2lds16(A + (size_t)(srow + 64) * N + k0 + scol,  &As[0][(srow + 64) * 32 + scol]);
        gl2lds16(B + (size_t)srow * N + k0 + scol,         &Bs[0][srow * 32 + scol]);
        gl2lds16(B + (size_t)(srow + 64) * N + k0 + scol,  &Bs[0][(srow + 64) * 32 + scol]);
        gl2lds16(B + (size_t)(srow + 128) * N + k0 + scol, &Bs[0][(srow + 128) * 32 + scol]);
        gl2lds16(B + (size_t)(srow + 192) * N + k0 + scol, &Bs[0][(srow + 192) * 32 + scol]);
    }

    for (int it = 0; it < nit; it++) {
        int cur = it & 1, nxt = cur ^ 1;
        __syncthreads();   // drains vmcnt: cur's stage was issued a full iteration ago
        if (it + 1 < nit) {
            int k0 = k_begin + (it + 1) * 32;
            gl2lds16(A + (size_t)srow * N + k0 + scol,         &As[nxt][srow * 32 + scol]);
            gl2lds16(A + (size_t)(srow + 64) * N + k0 + scol,  &As[nxt][(srow + 64) * 32 + scol]);
            gl2lds16(B + (size_t)srow * N + k0 + scol,         &Bs[nxt][srow * 32 + scol]);
            gl2lds16(B + (size_t)(srow + 64) * N + k0 + scol,  &Bs[nxt][(srow + 64) * 32 + scol]);
            gl2lds16(B + (size_t)(srow + 128) * N + k0 + scol, &Bs[nxt][(srow + 128) * 32 + scol]);
            gl2lds16(B + (size_t)(srow + 192) * N + k0 + scol, &Bs[nxt][(srow + 192) * 32 + scol]);
        }

        bf16x8 a[4];
        #pragma unroll
        for (int i = 0; i < 4; i++)
            a[i] = *(const bf16x8*)&As[cur][(wm * 64 + i * 16 + l16) * 32 + quad * 8];
        #pragma unroll
        for (int j = 0; j < 8; j++) {
            bf16x8 b = *(const bf16x8*)&Bs[cur][(wn * 128 + j * 16 + l16) * 32 + quad * 8];
            #pragma unroll
            for (int i = 0; i < 4; i++)
                acc[i][j] = __builtin_amdgcn_mfma_f32_16x16x32_bf16(a[i], b, acc[i][j], 0, 0, 0);
        }
    }

    // epilogue: C/D layout col = lane&15, row = quad*4 + r; strictly-lower mask s < t
    unsigned short* Sh = S + (size_t)ks * NH * T * T + (size_t)h * T * T;
    #pragma unroll
    for (int i = 0; i < 4; i++) {
        int t_base = bi * 128 + wm * 64 + i * 16 + quad * 4;
        #pragma unroll
        for (int j = 0; j < 8; j++) {
            int s_g = bj * 256 + wn * 128 + j * 16 + l16;
            #pragma unroll
            for (int r = 0; r < 4; r++) {
                int t_g = t_base + r;
                float v = (s_g < t_g) ? acc[i][j][r] : 0.0f;
                Sh[(size_t)t_g * T + s_g] = f2bf(v);
            }
        }
    }
}

// ---------------- GEMM2 v2: double-buffered LDS, 1 barrier/iter, B reg-hoist ----------
// grid = NH * 2(dblk) * 72(chunk tasks, 256-wide); flattened loop is k0-major/ks-minor so
// the Vt tile is staged once per k0 (and its frags live in registers across KS ks-iters).
__global__ __launch_bounds__(256) void gemm2_kernel(const unsigned short* __restrict__ S,
                                                    const unsigned short* __restrict__ Vt,
                                                    float* __restrict__ out, int KS) {
    __shared__ __align__(16) unsigned short As[2][128 * 32];   // 8 KB each
    __shared__ __align__(16) unsigned short Bs[2][128 * 32];   // 8 KB each

    int bx = blockIdx.x;
    int per_h = 2 * 72;
    int h = bx / per_h;
    int rem = bx % per_h;
    int dblk = rem / 72;
    int tc = rem % 72;
    // decode (bi, chunk): nc(bi) = ceil((bi+1)*128/256) = (bi+2)>>1, sum = 72
    int bi = 0, cum = 0;
    for (; bi < 16; bi++) { int nc = (bi + 2) >> 1; if (cum + nc > tc) break; cum += nc; }
    int c = tc - cum;

    int kend = (bi + 1) * 128;
    int cstart = c * 256;
    int clen = min(256, kend - cstart);   // 128 or 256
    int cpk = clen >> 5;                  // K-steps per ks: 4 or 8
    int ls = (KS == 4) ? 2 : (KS == 2) ? 1 : 0;
    int nit = cpk << ls;                  // total flattened iterations

    const unsigned short* Sh = S + (size_t)h * T * T + (size_t)bi * 128 * T + cstart;
    const size_t sstride = (size_t)NH * T * T;      // stride between ks split buffers
    const unsigned short* B = Vt + (size_t)dblk * 128 * T + cstart;

    int tid = threadIdx.x;
    int lane = tid & 63, wave = tid >> 6;
    int wm = wave >> 1, wn = wave & 1;
    int quad = lane >> 4, l16 = lane & 15;
    int srow = tid >> 2;
    int scol = (tid & 3) * 8;

    f32x4 acc[4][4];
    #pragma unroll
    for (int i = 0; i < 4; i++)
        #pragma unroll
        for (int j = 0; j < 4; j++)
            #pragma unroll
            for (int r = 0; r < 4; r++) acc[i][j][r] = 0.0f;

    // prologue: stage iter 0 (ks=0, k0=0) into buffer 0
    gl2lds16(Sh + (size_t)srow * T + scol,        &As[0][srow * 32 + scol]);
    gl2lds16(Sh + (size_t)(srow + 64) * T + scol, &As[0][(srow + 64) * 32 + scol]);
    gl2lds16(B + (size_t)srow * T + scol,         &Bs[0][srow * 32 + scol]);
    gl2lds16(B + (size_t)(srow + 64) * T + scol,  &Bs[0][(srow + 64) * 32 + scol]);

    bf16x8 b[4];
    for (int i = 0; i < nit; i++) {
        int k0i = i >> ls;
        int ks  = i & (KS - 1);
        __syncthreads();   // drains vmcnt: current buffers were staged a full iter ago
        if (i + 1 < nit) {
            int ksn = (i + 1) & (KS - 1);
            int k0n = (i + 1) >> ls;
            const unsigned short* An = Sh + (size_t)ksn * sstride + k0n * 32;
            int pan = (i + 1) & 1;
            gl2lds16(An + (size_t)srow * T + scol,        &As[pan][srow * 32 + scol]);
            gl2lds16(An + (size_t)(srow + 64) * T + scol, &As[pan][(srow + 64) * 32 + scol]);
            if (ksn == 0) {   // next iter starts a new k0 -> fresh Vt tile
                const unsigned short* Bn = B + k0n * 32;
                int pbn = k0n & 1;
                gl2lds16(Bn + (size_t)srow * T + scol,        &Bs[pbn][srow * 32 + scol]);
                gl2lds16(Bn + (size_t)(srow + 64) * T + scol, &Bs[pbn][(srow + 64) * 32 + scol]);
            }
        }

        int pa = i & 1, pb = k0i & 1;
        if (ks == 0) {   // Vt frags are identical across the KS ks-iterations of this k0
            #pragma unroll
            for (int j = 0; j < 4; j++)
                b[j] = *(const bf16x8*)&Bs[pb][(wn * 64 + j * 16 + l16) * 32 + quad * 8];
        }
        bf16x8 a[4];
        #pragma unroll
        for (int ii = 0; ii < 4; ii++)
            a[ii] = *(const bf16x8*)&As[pa][(wm * 64 + ii * 16 + l16) * 32 + quad * 8];
        #pragma unroll
        for (int ii = 0; ii < 4; ii++)
            #pragma unroll
            for (int j = 0; j < 4; j++)
                acc[ii][j] = __builtin_amdgcn_mfma_f32_16x16x32_bf16(a[ii], b[j], acc[ii][j], 0, 0, 0);
    }

    float* oh = out + (size_t)h * T * D;
    #pragma unroll
    for (int i = 0; i < 4; i++) {
        int t_base = bi * 128 + wm * 64 + i * 16 + quad * 4;
        #pragma unroll
        for (int j = 0; j < 4; j++) {
            int d_g = dblk * 128 + wn * 64 + j * 16 + l16;
            #pragma unroll
            for (int r = 0; r < 4; r++) {
                int t_g = t_base + r;
                atomicAdd(&oh[(size_t)t_g * D + d_g], acc[i][j][r]);
            }
        }
    }
}

extern "C" void kernel_launch(void* const* d_in, const int* in_sizes, int n_in,
                              void* d_out, int out_size, void* d_ws, size_t ws_size,
                              hipStream_t stream) {
    const float* Q = (const float*)d_in[0];   // (1, 4, 2048, 8192) fp32
    const float* V = (const float*)d_in[1];   // (1, 1, 2048, 256)  fp32
    float* out = (float*)d_out;               // (1, 4, 2048, 256)  fp32

    const size_t qr_elems = (size_t)NH * T * N;   // 67.1M
    const size_t vt_elems = (size_t)D * T;        // 0.5M
    const size_t s_elems  = (size_t)NH * T * T;   // 16.8M per split

    // largest KS in {4,2,1} that fits (KS must divide N/32 -> powers of 2)
    int KS = 1;
    for (int cand : {4, 2, 1}) {
        if (ws_size >= (qr_elems + vt_elems + (size_t)cand * s_elems) * sizeof(unsigned short)) {
            KS = cand; break;
        }
    }
    if (ws_size < (qr_elems + vt_elems + (size_t)KS * s_elems) * sizeof(unsigned short)) return;

    unsigned short* QR = (unsigned short*)d_ws;
    unsigned short* Vt = QR + qr_elems;
    unsigned short* S  = Vt + vt_elems;   // KS consecutive buffers of s_elems

    rope_kernel<<<(NH * T * N / 4) / 256, 256, 0, stream>>>(Q, QR);
    vt_kernel<<<(T / 64) * (D / 64), 256, 0, stream>>>(V, Vt);
    gemm1_kernel<<<NH * 72 * KS, 256, 0, stream>>>(QR, S, KS);
    hipMemsetAsync(d_out, 0, (size_t)out_size * sizeof(float), stream);
    gemm2_kernel<<<NH * 2 * 72, 256, 0, stream>>>(S, Vt, out, KS);
}

// Round 2
// 578.596 us; speedup vs baseline: 1.0433x; 1.0433x over previous
//
#include <hip/hip_runtime.h>

#define LDS_AS __attribute__((address_space(3)))
#define GLB_AS __attribute__((address_space(1)))

typedef __attribute__((ext_vector_type(8))) short bf16x8;   // 8 bf16 = 4 VGPRs (A/B frag)
typedef __attribute__((ext_vector_type(4))) float f32x4;    // C/D frag

static constexpr int NH = 4;
static constexpr int T  = 2048;
static constexpr int N  = 8192;
static constexpr int D  = 256;

__device__ inline unsigned short f2bf(float f) {
    unsigned int u = __float_as_uint(f);
    u += 0x7FFFu + ((u >> 16) & 1u);   // round-to-nearest-even
    return (unsigned short)(u >> 16);
}

__device__ inline void gl2lds16(const void* g, void* l) {
    __builtin_amdgcn_global_load_lds((GLB_AS void*)g, (LDS_AS void*)l, 16, 0, 0);
}

// ---------------- RoPE + bf16 cast: QR[h][t][n] ----------------
__global__ void rope_kernel(const float* __restrict__ Q, unsigned short* __restrict__ QR) {
    int g = blockIdx.x * 256 + threadIdx.x;     // one thread = 4 consecutive elements
    int base = g << 2;
    int n = base & (N - 1);
    int t = (base >> 13) & (T - 1);
    const float4 q = *(const float4*)(Q + (size_t)base);
    float tf = (float)t;
    const float inv2pi = 0.15915494309189535f;
    float f0 = exp2f((float)n       * (-1.0f / 512.0f)) * inv2pi;
    float f1 = exp2f((float)(n + 2) * (-1.0f / 512.0f)) * inv2pi;
    float r0 = tf * f0; r0 -= floorf(r0);
    float r1 = tf * f1; r1 -= floorf(r1);
    float s0 = __builtin_amdgcn_sinf(r0), c0 = __builtin_amdgcn_cosf(r0);
    float s1 = __builtin_amdgcn_sinf(r1), c1 = __builtin_amdgcn_cosf(r1);
    ushort4 o;
    o.x = f2bf(q.x * c0 - q.y * s0);
    o.y = f2bf(q.y * c0 + q.x * s0);
    o.z = f2bf(q.z * c1 - q.w * s1);
    o.w = f2bf(q.w * c1 + q.z * s1);
    *(ushort4*)(QR + (size_t)base) = o;
}

// ---------------- V -> Vt bf16 transpose via LDS: Vt[d][t] = bf16(V[t][d]) ----------------
__global__ void vt_kernel(const float* __restrict__ V, unsigned short* __restrict__ Vt) {
    __shared__ unsigned short tile[64 * 65];
    int tb = blockIdx.x >> 2, db = blockIdx.x & 3;
    int t0 = tb * 64, d0 = db * 64;
    int tid = threadIdx.x;
    #pragma unroll
    for (int r = 0; r < 16; r++) {
        int idx = tid + r * 256;
        int tl = idx >> 6, dl = idx & 63;
        tile[tl * 65 + dl] = f2bf(V[(size_t)(t0 + tl) * D + d0 + dl]);
    }
    __syncthreads();
    #pragma unroll
    for (int r = 0; r < 16; r++) {
        int idx = tid + r * 256;
        int dl = idx >> 6, tl = idx & 63;
        Vt[(size_t)(d0 + dl) * T + t0 + tl] = tile[tl * 65 + dl];
    }
}

// ---------------- GEMM1 v4: 128(t) x 256(s) tile, TRIPLE-buffer LDS, counted vmcnt ----
// Depth-2 prefetch pipeline: stage tile t+2 while computing tile t; s_waitcnt vmcnt(6)
// (= tile t+1's 6 loads still in flight) + raw s_barrier per iteration — never drain.
// Hazards: (1) tile-t data valid block-wide: each wave's own vmcnt(6) retires its tile-t
// loads, barrier publishes; (2) stage t+2 overwrites buf of t-1: all waves' ds_reads of
// t-1 retired (lgkmcnt before MFMA) before they reached barrier t, and the stage issues
// after barrier t.  4 waves as 2x2; wave tile 64x128 (4 x 8 frags of 16x16).
__global__ __launch_bounds__(256, 2) void gemm1_kernel(const unsigned short* __restrict__ QR,
                                                       unsigned short* __restrict__ S, int KS) {
    __shared__ __align__(16) unsigned short As[3][128 * 32];   // 8 KB each
    __shared__ __align__(16) unsigned short Bs[3][256 * 32];   // 16 KB each (total 72 KB)

    int bx = blockIdx.x;
    int per_h = 72 * KS;
    int h = bx / per_h;
    int rem = bx % per_h;
    int task = rem / KS;
    int ks = rem % KS;
    // decode (bi, bj): bj in [0, bi/2]; counts 1,1,2,2,...,8,8 sum=72
    int bi = 0, cum = 0;
    for (; bi < 16; bi++) { int nb = (bi >> 1) + 1; if (cum + nb > task) break; cum += nb; }
    int bj = task - cum;

    const unsigned short* A = QR + (size_t)h * T * N + (size_t)bi * 128 * N;
    const unsigned short* B = QR + (size_t)h * T * N + (size_t)bj * 256 * N;

    int KN = N / KS;
    int k_begin = ks * KN;
    int nit = KN / 32;

    int tid = threadIdx.x;
    int lane = tid & 63, wave = tid >> 6;
    int wm = wave >> 1, wn = wave & 1;
    int quad = lane >> 4, l16 = lane & 15;
    int srow = tid >> 2;
    int scol = (tid & 3) * 8;

    f32x4 acc[4][8];
    #pragma unroll
    for (int i = 0; i < 4; i++)
        #pragma unroll
        for (int j = 0; j < 8; j++)
            #pragma unroll
            for (int r = 0; r < 4; r++) acc[i][j][r] = 0.0f;

    // prologue: stage tiles 0 and 1 into buffers 0 and 1 (12 loads in flight)
    #pragma unroll
    for (int p = 0; p < 2; p++) {
        int k0 = k_begin + p * 32;
        gl2lds16(A + (size_t)srow * N + k0 + scol,         &As[p][srow * 32 + scol]);
        gl2lds16(A + (size_t)(srow + 64) * N + k0 + scol,  &As[p][(srow + 64) * 32 + scol]);
        gl2lds16(B + (size_t)srow * N + k0 + scol,         &Bs[p][srow * 32 + scol]);
        gl2lds16(B + (size_t)(srow + 64) * N + k0 + scol,  &Bs[p][(srow + 64) * 32 + scol]);
        gl2lds16(B + (size_t)(srow + 128) * N + k0 + scol, &Bs[p][(srow + 128) * 32 + scol]);
        gl2lds16(B + (size_t)(srow + 192) * N + k0 + scol, &Bs[p][(srow + 192) * 32 + scol]);
    }

    int cur = 0, nxt2 = 2;   // buffer of tile it, buffer of tile it+2
    for (int it = 0; it < nit; it++) {
        if (it + 1 < nit) {
            asm volatile("s_waitcnt vmcnt(6)" ::: "memory");   // tile it landed (own 6)
        } else {
            asm volatile("s_waitcnt vmcnt(0)" ::: "memory");   // final tile: drain
        }
        __builtin_amdgcn_s_barrier();            // block-wide: tile it valid, t-1 reads done
        __builtin_amdgcn_sched_barrier(0);       // pin ds_reads below the barrier

        bf16x8 a[4], b[8];
        #pragma unroll
        for (int i = 0; i < 4; i++)
            a[i] = *(const bf16x8*)&As[cur][(wm * 64 + i * 16 + l16) * 32 + quad * 8];
        #pragma unroll
        for (int j = 0; j < 8; j++)
            b[j] = *(const bf16x8*)&Bs[cur][(wn * 128 + j * 16 + l16) * 32 + quad * 8];

        if (it + 2 < nit) {                      // stage tile it+2 (overwrites buf of it-1)
            int k0 = k_begin + (it + 2) * 32;
            gl2lds16(A + (size_t)srow * N + k0 + scol,         &As[nxt2][srow * 32 + scol]);
            gl2lds16(A + (size_t)(srow + 64) * N + k0 + scol,  &As[nxt2][(srow + 64) * 32 + scol]);
            gl2lds16(B + (size_t)srow * N + k0 + scol,         &Bs[nxt2][srow * 32 + scol]);
            gl2lds16(B + (size_t)(srow + 64) * N + k0 + scol,  &Bs[nxt2][(srow + 64) * 32 + scol]);
            gl2lds16(B + (size_t)(srow + 128) * N + k0 + scol, &Bs[nxt2][(srow + 128) * 32 + scol]);
            gl2lds16(B + (size_t)(srow + 192) * N + k0 + scol, &Bs[nxt2][(srow + 192) * 32 + scol]);
        }

        __builtin_amdgcn_s_setprio(1);
        #pragma unroll
        for (int j = 0; j < 8; j++)
            #pragma unroll
            for (int i = 0; i < 4; i++)
                acc[i][j] = __builtin_amdgcn_mfma_f32_16x16x32_bf16(a[i], b[j], acc[i][j], 0, 0, 0);
        __builtin_amdgcn_s_setprio(0);

        cur  = (cur  == 2) ? 0 : cur  + 1;
        nxt2 = (nxt2 == 2) ? 0 : nxt2 + 1;
    }

    // epilogue: C/D layout col = lane&15, row = quad*4 + r; strictly-lower mask s < t
    unsigned short* Sh = S + (size_t)ks * NH * T * T + (size_t)h * T * T;
    #pragma unroll
    for (int i = 0; i < 4; i++) {
        int t_base = bi * 128 + wm * 64 + i * 16 + quad * 4;
        #pragma unroll
        for (int j = 0; j < 8; j++) {
            int s_g = bj * 256 + wn * 128 + j * 16 + l16;
            #pragma unroll
            for (int r = 0; r < 4; r++) {
                int t_g = t_base + r;
                float v = (s_g < t_g) ? acc[i][j][r] : 0.0f;
                Sh[(size_t)t_g * T + s_g] = f2bf(v);
            }
        }
    }
}

// ---------------- GEMM2 v2: double-buffered LDS, 1 barrier/iter, B reg-hoist ----------
// grid = NH * 2(dblk) * 72(chunk tasks, 256-wide); flattened loop is k0-major/ks-minor so
// the Vt tile is staged once per k0 (and its frags live in registers across KS ks-iters).
__global__ __launch_bounds__(256) void gemm2_kernel(const unsigned short* __restrict__ S,
                                                    const unsigned short* __restrict__ Vt,
                                                    float* __restrict__ out, int KS) {
    __shared__ __align__(16) unsigned short As[2][128 * 32];   // 8 KB each
    __shared__ __align__(16) unsigned short Bs[2][128 * 32];   // 8 KB each

    int bx = blockIdx.x;
    int per_h = 2 * 72;
    int h = bx / per_h;
    int rem = bx % per_h;
    int dblk = rem / 72;
    int tc = rem % 72;
    // decode (bi, chunk): nc(bi) = ceil((bi+1)*128/256) = (bi+2)>>1, sum = 72
    int bi = 0, cum = 0;
    for (; bi < 16; bi++) { int nc = (bi + 2) >> 1; if (cum + nc > tc) break; cum += nc; }
    int c = tc - cum;

    int kend = (bi + 1) * 128;
    int cstart = c * 256;
    int clen = min(256, kend - cstart);   // 128 or 256
    int cpk = clen >> 5;                  // K-steps per ks: 4 or 8
    int ls = (KS == 4) ? 2 : (KS == 2) ? 1 : 0;
    int nit = cpk << ls;                  // total flattened iterations

    const unsigned short* Sh = S + (size_t)h * T * T + (size_t)bi * 128 * T + cstart;
    const size_t sstride = (size_t)NH * T * T;      // stride between ks split buffers
    const unsigned short* B = Vt + (size_t)dblk * 128 * T + cstart;

    int tid = threadIdx.x;
    int lane = tid & 63, wave = tid >> 6;
    int wm = wave >> 1, wn = wave & 1;
    int quad = lane >> 4, l16 = lane & 15;
    int srow = tid >> 2;
    int scol = (tid & 3) * 8;

    f32x4 acc[4][4];
    #pragma unroll
    for (int i = 0; i < 4; i++)
        #pragma unroll
        for (int j = 0; j < 4; j++)
            #pragma unroll
            for (int r = 0; r < 4; r++) acc[i][j][r] = 0.0f;

    // prologue: stage iter 0 (ks=0, k0=0) into buffer 0
    gl2lds16(Sh + (size_t)srow * T + scol,        &As[0][srow * 32 + scol]);
    gl2lds16(Sh + (size_t)(srow + 64) * T + scol, &As[0][(srow + 64) * 32 + scol]);
    gl2lds16(B + (size_t)srow * T + scol,         &Bs[0][srow * 32 + scol]);
    gl2lds16(B + (size_t)(srow + 64) * T + scol,  &Bs[0][(srow + 64) * 32 + scol]);

    bf16x8 b[4];
    for (int i = 0; i < nit; i++) {
        int k0i = i >> ls;
        int ks  = i & (KS - 1);
        __syncthreads();   // drains vmcnt: current buffers were staged a full iter ago
        if (i + 1 < nit) {
            int ksn = (i + 1) & (KS - 1);
            int k0n = (i + 1) >> ls;
            const unsigned short* An = Sh + (size_t)ksn * sstride + k0n * 32;
            int pan = (i + 1) & 1;
            gl2lds16(An + (size_t)srow * T + scol,        &As[pan][srow * 32 + scol]);
            gl2lds16(An + (size_t)(srow + 64) * T + scol, &As[pan][(srow + 64) * 32 + scol]);
            if (ksn == 0) {   // next iter starts a new k0 -> fresh Vt tile
                const unsigned short* Bn = B + k0n * 32;
                int pbn = k0n & 1;
                gl2lds16(Bn + (size_t)srow * T + scol,        &Bs[pbn][srow * 32 + scol]);
                gl2lds16(Bn + (size_t)(srow + 64) * T + scol, &Bs[pbn][(srow + 64) * 32 + scol]);
            }
        }

        int pa = i & 1, pb = k0i & 1;
        if (ks == 0) {   // Vt frags are identical across the KS ks-iterations of this k0
            #pragma unroll
            for (int j = 0; j < 4; j++)
                b[j] = *(const bf16x8*)&Bs[pb][(wn * 64 + j * 16 + l16) * 32 + quad * 8];
        }
        bf16x8 a[4];
        #pragma unroll
        for (int ii = 0; ii < 4; ii++)
            a[ii] = *(const bf16x8*)&As[pa][(wm * 64 + ii * 16 + l16) * 32 + quad * 8];
        #pragma unroll
        for (int ii = 0; ii < 4; ii++)
            #pragma unroll
            for (int j = 0; j < 4; j++)
                acc[ii][j] = __builtin_amdgcn_mfma_f32_16x16x32_bf16(a[ii], b[j], acc[ii][j], 0, 0, 0);
    }

    float* oh = out + (size_t)h * T * D;
    #pragma unroll
    for (int i = 0; i < 4; i++) {
        int t_base = bi * 128 + wm * 64 + i * 16 + quad * 4;
        #pragma unroll
        for (int j = 0; j < 4; j++) {
            int d_g = dblk * 128 + wn * 64 + j * 16 + l16;
            #pragma unroll
            for (int r = 0; r < 4; r++) {
                int t_g = t_base + r;
                atomicAdd(&oh[(size_t)t_g * D + d_g], acc[i][j][r]);
            }
        }
    }
}

extern "C" void kernel_launch(void* const* d_in, const int* in_sizes, int n_in,
                              void* d_out, int out_size, void* d_ws, size_t ws_size,
                              hipStream_t stream) {
    const float* Q = (const float*)d_in[0];   // (1, 4, 2048, 8192) fp32
    const float* V = (const float*)d_in[1];   // (1, 1, 2048, 256)  fp32
    float* out = (float*)d_out;               // (1, 4, 2048, 256)  fp32

    const size_t qr_elems = (size_t)NH * T * N;   // 67.1M
    const size_t vt_elems = (size_t)D * T;        // 0.5M
    const size_t s_elems  = (size_t)NH * T * T;   // 16.8M per split

    // largest KS in {4,2,1} that fits (KS must divide N/32 -> powers of 2)
    int KS = 1;
    for (int cand : {4, 2, 1}) {
        if (ws_size >= (qr_elems + vt_elems + (size_t)cand * s_elems) * sizeof(unsigned short)) {
            KS = cand; break;
        }
    }
    if (ws_size < (qr_elems + vt_elems + (size_t)KS * s_elems) * sizeof(unsigned short)) return;

    unsigned short* QR = (unsigned short*)d_ws;
    unsigned short* Vt = QR + qr_elems;
    unsigned short* S  = Vt + vt_elems;   // KS consecutive buffers of s_elems

    rope_kernel<<<(NH * T * N / 4) / 256, 256, 0, stream>>>(Q, QR);
    vt_kernel<<<(T / 64) * (D / 64), 256, 0, stream>>>(V, Vt);
    gemm1_kernel<<<NH * 72 * KS, 256, 0, stream>>>(QR, S, KS);
    hipMemsetAsync(d_out, 0, (size_t)out_size * sizeof(float), stream);
    gemm2_kernel<<<NH * 2 * 40 * 0 + NH * 2 * 72, 256, 0, stream>>>(S, Vt, out, KS);
}